// Round 1
// 657.031 us; speedup vs baseline: 1.1889x; 1.1889x over previous
//
#include <hip/hip_runtime.h>

typedef unsigned short u16;
typedef unsigned int u32;
typedef __attribute__((ext_vector_type(4))) float f32x4;
typedef __attribute__((ext_vector_type(4))) u16 u16x4;
typedef __attribute__((ext_vector_type(8))) u16 u16x8;
typedef __attribute__((ext_vector_type(8))) __bf16 bf16x8;

#define FLA_EPS 1e-6f

__device__ __forceinline__ u16 f2b(float f) {
  union { float f; u32 u; } v; v.f = f;
  u32 r = v.u + 0x7FFFu + ((v.u >> 16) & 1u);
  return (u16)(r >> 16);
}
__device__ __forceinline__ float b2f(u16 h) {
  union { u32 u; float f; } v; v.u = ((u32)h) << 16; return v.f;
}
__device__ __forceinline__ void g2l16(const void* g, void* l) {
  __builtin_amdgcn_global_load_lds((__attribute__((address_space(1))) void*)g,
                                   (__attribute__((address_space(3))) void*)l,
                                   16, 0, 0);
}

// ---------------- cast x fp32 -> bf16 ----------------
__global__ void __launch_bounds__(256) cast_f32_bf16(const float* __restrict__ in,
                                                     u16* __restrict__ out) {
  size_t i = (size_t)blockIdx.x * 256 + threadIdx.x;
  const f32x4* p = (const f32x4*)in + i * 2;
  f32x4 a = p[0], b = p[1];
  u16x8 r;
  r[0] = f2b(a[0]); r[1] = f2b(a[1]); r[2] = f2b(a[2]); r[3] = f2b(a[3]);
  r[4] = f2b(b[0]); r[5] = f2b(b[1]); r[6] = f2b(b[2]); r[7] = f2b(b[3]);
  ((u16x8*)out)[i] = r;
}

// ---------------- transpose + cast: Wt[n][k] = bf16(W[k][n]) ----------------
__global__ void __launch_bounds__(256) transpose_cast(const float* __restrict__ W,
                                                      u16* __restrict__ Wt, int dim) {
  __shared__ float tile[64][65];
  const int t = threadIdx.x;
  const int k0 = blockIdx.x * 64, n0 = blockIdx.y * 64;
  const int r = t >> 4, c4 = (t & 15) * 4;
#pragma unroll
  for (int i = 0; i < 4; ++i) {
    f32x4 vv = *(const f32x4*)(W + (size_t)(k0 + r + i * 16) * dim + n0 + c4);
    tile[r + i * 16][c4 + 0] = vv[0];
    tile[r + i * 16][c4 + 1] = vv[1];
    tile[r + i * 16][c4 + 2] = vv[2];
    tile[r + i * 16][c4 + 3] = vv[3];
  }
  __syncthreads();
#pragma unroll
  for (int i = 0; i < 4; ++i) {
    int nrow = r + i * 16;
    u16x4 o;
#pragma unroll
    for (int j = 0; j < 4; ++j) o[j] = f2b(tile[c4 + j][nrow]);
    *(u16x4*)(Wt + (size_t)(n0 + nrow) * dim + k0 + c4) = o;
  }
}

// ---------------- fold proj into Wq/Wk ----------------
__global__ void __launch_bounds__(256) fold_w(const float* __restrict__ Wq,
                                              const float* __restrict__ Wk,
                                              const float* __restrict__ proj,
                                              u16* __restrict__ WqkvT) {
  __shared__ float Wt[64][65];
  __shared__ float P[64][64];
  const int t = threadIdx.x;
  const int kbase = blockIdx.x * 64, h = blockIdx.y, sel = blockIdx.z;
  const float* W = sel ? Wk : Wq;
  {
    int row = t >> 2, cb = (t & 3) * 16;
#pragma unroll
    for (int i = 0; i < 4; ++i) {
      f32x4 vv = *(const f32x4*)(W + (size_t)(kbase + row) * 1024 + h * 64 + cb + i * 4);
      Wt[row][cb + i * 4 + 0] = vv[0]; Wt[row][cb + i * 4 + 1] = vv[1];
      Wt[row][cb + i * 4 + 2] = vv[2]; Wt[row][cb + i * 4 + 3] = vv[3];
      f32x4 pp = *(const f32x4*)(proj + (size_t)row * 64 + cb + i * 4);
      P[row][cb + i * 4 + 0] = pp[0]; P[row][cb + i * 4 + 1] = pp[1];
      P[row][cb + i * 4 + 2] = pp[2]; P[row][cb + i * 4 + 3] = pp[3];
    }
  }
  __syncthreads();
  const int kk = t & 63, fg = (t >> 6) * 16;
  float acc[16] = {};
  for (int d = 0; d < 64; ++d) {
    float w = Wt[kk][d];
#pragma unroll
    for (int ff = 0; ff < 16; ++ff) acc[ff] = fmaf(w, P[d][fg + ff], acc[ff]);
  }
#pragma unroll
  for (int ff = 0; ff < 16; ++ff)
    WqkvT[(size_t)(sel * 1024 + h * 64 + fg + ff) * 1024 + kbase + kk] = f2b(acc[ff]);
}

// ---------------- 256x256 BK=64 8-phase bf16 MFMA GEMM (T1+T2+T3+T4+T5) ----------------
// 512 thr = 8 waves (2M x 4N); per-wave C = 128x64 (8x4 frags of 16x16x32).
// LDS 128 KiB: 2 K-tile bufs x (A 256x64 + B 256x64) bf16, staged as 128-row halves
// via global_load_lds x16B (linear LDS dest, 3-bit XOR swizzle folded into the
// GLOBAL source column; ds_read applies the same XOR -> bank-conflict-free).
// Schedule/iter (2 K-tiles): 8 phases = 4 C-quadrants per tile; 1 half-tile staged
// per phase; counted vmcnt(4) ONLY at phases 4/8 (drains the tile consumed next,
// leaves 2 half-tiles in flight); raw s_barrier pairs; setprio(1) around MFMAs.
// Stage-issue for a region always sits after the barrier that follows its last
// ds_read (WAR-safe); reads sit after the vmcnt+barrier draining their producer.
template <int NB, bool QKV>
__global__ void __launch_bounds__(512, 2) gemm256(const u16* __restrict__ Ax,
                                                  const u16* __restrict__ Bt,
                                                  u16* __restrict__ qo, u16* __restrict__ ko,
                                                  u16* __restrict__ vo,
                                                  float* __restrict__ Cf,
                                                  const float* __restrict__ bias) {
  extern __shared__ __align__(16) u16 lds[];
  const int tid = threadIdx.x;
  // XCD swizzle: flat&7 = xcd; per XCD 16 m-blocks as 2 chunks of 8; n-major groups
  // so one 4MB A-chunk stays L2-resident while B strips (0.5MB) stream.
  const int flat = blockIdx.x;
  const int xcd = flat & 7, slot = flat >> 3;
  const int pos = slot & 7, g = slot >> 3;
  const int nc = g % NB, mc = g / NB;
  const int m0 = (xcd * 16 + mc * 8 + pos) * 256;
  const int n0 = nc * 256;
  const int w = tid >> 6, l = tid & 63, quad = l >> 4, lr = l & 15;
  const int wm = w >> 2, wn = w & 3;
  u16* const A0 = lds;                // buf0 A (2 halves of 8192 u16)
  u16* const B0 = lds + 16384;        // buf0 B
  u16* const A1 = lds + 32768;        // buf1 A
  u16* const B1 = lds + 49152;        // buf1 B
  // per-thread constant swizzled k-columns (u16 units) for the two ks slots
  const int c0 = ((quad * 16) ^ ((lr & 7) << 4)) >> 1;
  const int c1 = ((64 + quad * 16) ^ ((lr & 7) << 4)) >> 1;
  // staging constants: thread covers row rst (+64 for 2nd load), source col pre-swizzled
  const int rst = tid >> 3;
  const int ksw8 = ((tid & 7) ^ (rst & 7)) * 8;
  const int tid8 = tid * 8;

  f32x4 acc[8][4] = {};
  bf16x8 af[4][2], bf[4][2];

#define STG(SRC, ROW0, KT, DST) do {                                         \
    const u16* s_ = (SRC) + (size_t)((ROW0) + rst) * 1024 + (KT) + ksw8;     \
    g2l16(s_, (DST) + tid8);                                                 \
    g2l16(s_ + 64 * 1024, (DST) + 4096 + tid8);                              \
  } while (0)

#define LDA_(BASE, MH) do {                                                  \
    const u16* ap_ = (BASE) + wm * 8192;                                     \
    _Pragma("unroll")                                                        \
    for (int ii = 0; ii < 4; ++ii) {                                         \
      const int ro_ = ((MH) * 64 + ii * 16 + lr) * 64;                       \
      af[ii][0] = *(const bf16x8*)(ap_ + ro_ + c0);                          \
      af[ii][1] = *(const bf16x8*)(ap_ + ro_ + c1);                          \
    } } while (0)

#define LDB_(BASE, NH) do {                                                  \
    const u16* bp_ = (BASE) + (wn >> 1) * 8192 + (wn & 1) * 4096;            \
    _Pragma("unroll")                                                        \
    for (int jj = 0; jj < 2; ++jj) {                                         \
      const int ro_ = (((NH) * 2 + jj) * 16 + lr) * 64;                      \
      bf[(NH) * 2 + jj][0] = *(const bf16x8*)(bp_ + ro_ + c0);               \
      bf[(NH) * 2 + jj][1] = *(const bf16x8*)(bp_ + ro_ + c1);               \
    } } while (0)

#define MFMA16(MH, NH)                                                       \
    _Pragma("unroll")                                                        \
    for (int ii = 0; ii < 4; ++ii)                                           \
      _Pragma("unroll")                                                      \
      for (int jj = 0; jj < 2; ++jj)                                         \
        _Pragma("unroll")                                                    \
        for (int ks = 0; ks < 2; ++ks)                                       \
          acc[(MH) * 4 + ii][(NH) * 2 + jj] =                                \
              __builtin_amdgcn_mfma_f32_16x16x32_bf16(                       \
                  af[ii][ks], bf[(NH) * 2 + jj][ks],                         \
                  acc[(MH) * 4 + ii][(NH) * 2 + jj], 0, 0, 0);

#define BARMFMA(MH, NH) do {                                                 \
    __builtin_amdgcn_s_barrier();                                            \
    asm volatile("s_waitcnt lgkmcnt(0)" ::: "memory");                       \
    __builtin_amdgcn_sched_barrier(0);                                       \
    __builtin_amdgcn_s_setprio(1);                                           \
    MFMA16(MH, NH);                                                          \
    __builtin_amdgcn_s_setprio(0);                                           \
    __builtin_amdgcn_s_barrier();                                            \
  } while (0)

  // prologue: T0 -> buf0 complete; T1 B-halves -> buf1 (T1 A staged at p1/p2)
  STG(Ax, m0, 0, A0);  STG(Ax, m0 + 128, 0, A0 + 8192);
  STG(Bt, n0, 0, B0);  STG(Bt, n0 + 128, 0, B0 + 8192);
  STG(Bt, n0, 64, B1); STG(Bt, n0 + 128, 64, B1 + 8192);
  asm volatile("s_waitcnt vmcnt(4)" ::: "memory");   // T0's 8 loads drained
  __builtin_amdgcn_s_barrier();

  for (int it = 0; it < 8; ++it) {
    const bool lastI = (it == 7);
    const int ko = it * 128;
    // ---- tile 2it from buf0 ----
    // p1: (m0-3 x n0-1); stage T(2it+1)-A half0
    LDA_(A0, 0); LDB_(B0, 0);
    STG(Ax, m0, ko + 64, A1);
    BARMFMA(0, 0);
    // p2: (m0-3 x n2-3); stage T(2it+1)-A half1
    LDB_(B0, 1);
    STG(Ax, m0 + 128, ko + 64, A1 + 8192);
    BARMFMA(0, 1);
    // p3: (m4-7 x n0-1); B0 reads done at p2 -> stage T(2it+2)-B half0
    LDA_(A0, 1);
    if (!lastI) STG(Bt, n0, ko + 128, B0);
    BARMFMA(1, 0);
    // p4: (m4-7 x n2-3); stage T(2it+2)-B half1; counted drain of T(2it+1)
    if (!lastI) {
      STG(Bt, n0 + 128, ko + 128, B0 + 8192);
      asm volatile("s_waitcnt vmcnt(4)" ::: "memory");
    } else {
      asm volatile("s_waitcnt vmcnt(0)" ::: "memory");
    }
    BARMFMA(1, 1);
    // ---- tile 2it+1 from buf1 ----
    // p5: stage T(2it+2)-A half0 (buf0 A reads ended at p3)
    LDA_(A1, 0); LDB_(B1, 0);
    if (!lastI) STG(Ax, m0, ko + 128, A0);
    BARMFMA(0, 0);
    // p6: stage T(2it+2)-A half1
    LDB_(B1, 1);
    if (!lastI) STG(Ax, m0 + 128, ko + 128, A0 + 8192);
    BARMFMA(0, 1);
    // p7: stage T(2it+3)-B half0 (buf1 B reads ended at p6)
    LDA_(A1, 1);
    if (!lastI) STG(Bt, n0, ko + 192, B1);
    BARMFMA(1, 0);
    // p8: stage T(2it+3)-B half1; counted drain of T(2it+2)
    if (!lastI) {
      STG(Bt, n0 + 128, ko + 192, B1 + 8192);
      asm volatile("s_waitcnt vmcnt(4)" ::: "memory");
    }
    BARMFMA(1, 1);
  }
#undef STG
#undef LDA_
#undef LDB_
#undef MFMA16
#undef BARMFMA

  const int rbase = m0 + wm * 128 + quad * 4;
  if (QKV) {
    const int sel = n0 >> 10;
    u16* dst = (sel == 0) ? qo : ((sel == 1) ? ko : vo);
    const int cb = (n0 & 1023) + wn * 64 + lr;
#pragma unroll
    for (int mi = 0; mi < 8; ++mi)
#pragma unroll
      for (int nj = 0; nj < 4; ++nj)
#pragma unroll
        for (int rr = 0; rr < 4; ++rr) {
          int row = rbase + mi * 16 + rr;
          float v = acc[mi][nj][rr];
          if (sel < 2) v = fmaxf(v, 0.0f) + FLA_EPS;
          dst[(size_t)row * 1024 + cb + nj * 16] = f2b(v);
        }
  } else {
    const int cb = n0 + wn * 64 + lr;
#pragma unroll
    for (int mi = 0; mi < 8; ++mi)
#pragma unroll
      for (int nj = 0; nj < 4; ++nj)
#pragma unroll
        for (int rr = 0; rr < 4; ++rr) {
          int row = rbase + mi * 16 + rr;
          Cf[(size_t)row * 1024 + cb + nj * 16] = acc[mi][nj][rr] + bias[cb + nj * 16];
        }
  }
}

// ---------------- kv partials ----------------
__global__ void __launch_bounds__(256) kv_partial(const u16* __restrict__ kf,
                                                  const u16* __restrict__ v,
                                                  float* __restrict__ part,
                                                  float* __restrict__ ksum_p) {
  const int t = threadIdx.x;
  const int bh = blockIdx.x, b = bh >> 4, h = bh & 15;
  const int w = t >> 6, l = t & 63;
  const int sub = blockIdx.y * 4 + w;
  const int f0 = (l >> 3) * 8, d0 = (l & 7) * 8;
  const size_t rowbase = ((size_t)b * 8192 + (size_t)sub * 256) * 1024 + h * 64;
  float acc[8][8] = {};
  float ks[8] = {};
#pragma unroll 2
  for (int n = 0; n < 256; ++n) {
    u16x8 ka = *(const u16x8*)(kf + rowbase + (size_t)n * 1024 + f0);
    u16x8 va = *(const u16x8*)(v + rowbase + (size_t)n * 1024 + d0);
    float kff[8], vf[8];
#pragma unroll
    for (int i = 0; i < 8; ++i) { kff[i] = b2f(ka[i]); vf[i] = b2f(va[i]); }
#pragma unroll
    for (int i = 0; i < 8; ++i) {
      ks[i] += kff[i];
#pragma unroll
      for (int j = 0; j < 8; ++j) acc[i][j] = fmaf(kff[i], vf[j], acc[i][j]);
    }
  }
  float* pb = part + ((size_t)bh * 32 + sub) * 4096;
#pragma unroll
  for (int j = 0; j < 8; ++j)
#pragma unroll
    for (int i = 0; i < 8; i += 4) {
      f32x4 vv = { acc[i][j], acc[i + 1][j], acc[i + 2][j], acc[i + 3][j] };
      *(f32x4*)(pb + (d0 + j) * 64 + f0 + i) = vv;
    }
  if (d0 == 0) {
    float* kp = ksum_p + ((size_t)bh * 32 + sub) * 64 + f0;
    f32x4 a = { ks[0], ks[1], ks[2], ks[3] }, bq = { ks[4], ks[5], ks[6], ks[7] };
    *(f32x4*)(kp) = a; *(f32x4*)(kp + 4) = bq;
  }
}

__global__ void __launch_bounds__(256) reduce_kv(const float* __restrict__ part,
                                                 float* __restrict__ kvT) {
  int i = blockIdx.x * 256 + threadIdx.x;
  int bh = i >> 12, dfi = i & 4095;
  const float* p = part + (size_t)bh * 32 * 4096 + dfi;
  float s = 0.f;
#pragma unroll
  for (int sub = 0; sub < 32; ++sub) s += p[(size_t)sub * 4096];
  kvT[i] = s;
}

// ---------------- num/den + normalize ----------------
__global__ void __launch_bounds__(256) num_den(const u16* __restrict__ qf,
                                               const float* __restrict__ kvT,
                                               const float* __restrict__ ksum_p,
                                               u16* __restrict__ outI) {
  __shared__ __align__(16) u16 As[128 * 64];
  __shared__ __align__(16) u16 Bs[64 * 64];
  __shared__ float ksum_s[64];
  __shared__ float den_s[128];
  const int t = threadIdx.x;
  const size_t tok0 = (size_t)blockIdx.x * 128;
  const int h = blockIdx.y;
  const int bh = (blockIdx.x >> 6) * 16 + h;
  const int w = t >> 6, l = t & 63, quad = l >> 4, lr = l & 15;
  const int trow = t >> 3, tcol = (t & 7) * 8;
#pragma unroll
  for (int i = 0; i < 4; ++i) {
    int r = i * 32 + trow;
    g2l16(qf + (tok0 + r) * 1024 + h * 64 + tcol, &As[r * 64 + tcol]);
  }
  {
    const float* kvb = kvT + (size_t)bh * 4096;
    int d = t >> 2, cb = (t & 3) * 16;
    u16x8 o0, o1;
#pragma unroll
    for (int q4 = 0; q4 < 2; ++q4) {
      f32x4 vv = *(const f32x4*)(kvb + d * 64 + cb + q4 * 4);
      o0[q4 * 4 + 0] = f2b(vv[0]); o0[q4 * 4 + 1] = f2b(vv[1]);
      o0[q4 * 4 + 2] = f2b(vv[2]); o0[q4 * 4 + 3] = f2b(vv[3]);
    }
#pragma unroll
    for (int q4 = 0; q4 < 2; ++q4) {
      f32x4 vv = *(const f32x4*)(kvb + d * 64 + cb + 8 + q4 * 4);
      o1[q4 * 4 + 0] = f2b(vv[0]); o1[q4 * 4 + 1] = f2b(vv[1]);
      o1[q4 * 4 + 2] = f2b(vv[2]); o1[q4 * 4 + 3] = f2b(vv[3]);
    }
    *(u16x8*)&Bs[d * 64 + cb] = o0;
    *(u16x8*)&Bs[d * 64 + cb + 8] = o1;
  }
  if (t < 64) {
    float s = 0.f;
    const float* kp = ksum_p + (size_t)bh * 32 * 64 + t;
#pragma unroll
    for (int sub = 0; sub < 32; ++sub) s += kp[(size_t)sub * 64];
    ksum_s[t] = s;
  }
  __syncthreads();
  if (t < 128) {
    float d = FLA_EPS;
#pragma unroll
    for (int jj = 0; jj < 64; ++jj) {
      int f = (t + jj) & 63;
      d += b2f(As[t * 64 + f]) * ksum_s[f];
    }
    den_s[t] = d;
  }
  __syncthreads();
  f32x4 acc[2][4] = {};
  const int wrow = w * 32;
#pragma unroll
  for (int ks = 0; ks < 2; ++ks) {
    bf16x8 af[2], bfr[4];
#pragma unroll
    for (int i = 0; i < 2; ++i)
      af[i] = *(const bf16x8*)&As[(wrow + i * 16 + lr) * 64 + ks * 32 + quad * 8];
#pragma unroll
    for (int j = 0; j < 4; ++j)
      bfr[j] = *(const bf16x8*)&Bs[(j * 16 + lr) * 64 + ks * 32 + quad * 8];
#pragma unroll
    for (int i = 0; i < 2; ++i)
#pragma unroll
      for (int j = 0; j < 4; ++j)
        acc[i][j] = __builtin_amdgcn_mfma_f32_16x16x32_bf16(af[i], bfr[j], acc[i][j], 0, 0, 0);
  }
#pragma unroll
  for (int i = 0; i < 2; ++i)
#pragma unroll
    for (int j = 0; j < 4; ++j)
#pragma unroll
      for (int rr = 0; rr < 4; ++rr) {
        int rloc = wrow + i * 16 + quad * 4 + rr;
        float v = acc[i][j][rr] / den_s[rloc];
        outI[(tok0 + rloc) * 1024 + h * 64 + j * 16 + lr] = f2b(v);
      }
}

extern "C" void kernel_launch(void* const* d_in, const int* in_sizes, int n_in,
                              void* d_out, int out_size, void* d_ws, size_t ws_size,
                              hipStream_t stream) {
  const float* x    = (const float*)d_in[0];
  const float* Wq   = (const float*)d_in[1];
  const float* Wk   = (const float*)d_in[2];
  const float* Wv   = (const float*)d_in[3];
  const float* proj = (const float*)d_in[4];
  const float* Wo   = (const float*)d_in[5];
  const float* bo   = (const float*)d_in[6];
  float* out = (float*)d_out;

  char* ws = (char*)d_ws;
  const size_t SZ = 1ull << 26;
  u16* xb     = (u16*)(ws + 0);
  u16* qb     = (u16*)(ws + SZ);
  u16* kb     = (u16*)(ws + 2 * SZ);
  u16* vb     = (u16*)(ws + 3 * SZ);
  u16* WqkvT  = (u16*)(ws + 4 * SZ);
  u16* woT    = (u16*)(ws + 4 * SZ + 0x600000);
  float* part   = (float*)(ws + 4 * SZ + 0x800000);
  float* ksum_p = (float*)(ws + 4 * SZ + 0x800000 + 0x2000000);
  float* kvT    = (float*)(ws + 4 * SZ + 0x800000 + 0x2080000);

  static int attr_done = 0;
  if (!attr_done) {
    (void)hipFuncSetAttribute((const void*)gemm256<12, true>,
                              hipFuncAttributeMaxDynamicSharedMemorySize, 131072);
    (void)hipFuncSetAttribute((const void*)gemm256<4, false>,
                              hipFuncAttributeMaxDynamicSharedMemorySize, 131072);
    attr_done = 1;
  }

  cast_f32_bf16<<<16384, 256, 0, stream>>>(x, xb);
  fold_w<<<dim3(16, 16, 2), 256, 0, stream>>>(Wq, Wk, proj, WqkvT);
  transpose_cast<<<dim3(16, 16), 256, 0, stream>>>(Wv, WqkvT + (size_t)2048 * 1024, 1024);
  transpose_cast<<<dim3(16, 16), 256, 0, stream>>>(Wo, woT, 1024);
  gemm256<12, true><<<1536, 512, 131072, stream>>>(xb, WqkvT, qb, kb, vb, nullptr, nullptr);
  kv_partial<<<dim3(64, 8), 256, 0, stream>>>(kb, vb, part, ksum_p);
  reduce_kv<<<1024, 256, 0, stream>>>(part, kvT);
  num_den<<<dim3(256, 16), 256, 0, stream>>>(qb, kvT, ksum_p, xb);
  gemm256<4, false><<<512, 512, 131072, stream>>>(xb, woT, nullptr, nullptr, nullptr, out, bo);
}